// Round 1
// baseline (1769.410 us; speedup 1.0000x reference)
//
#include <hip/hip_runtime.h>
#include <math.h>

#define D 128

__device__ __forceinline__ float wsum(float v) {
    v += __shfl_xor(v, 1, 64);
    v += __shfl_xor(v, 2, 64);
    v += __shfl_xor(v, 4, 64);
    v += __shfl_xor(v, 8, 64);
    v += __shfl_xor(v, 16, 64);
    v += __shfl_xor(v, 32, 64);
    return v;
}

__device__ __forceinline__ void atomAddF(float* p, float v) {
    unsafeAtomicAdd(p, v);   // native global_atomic_add_f32 on gfx950
}

// ---------------------------------------------------------------- detect adj dtype
// int64 little-endian read as int32 -> odd words are all high-words (=0 since 0<=idx<N).
// int32 real data: odd words are random row indices, ~never all zero over 64 samples.
__global__ void detectk(const int* __restrict__ adj, int* __restrict__ flag) {
    int any = 0;
    for (int i = 0; i < 64; ++i) any |= adj[2 * i + 1];
    *flag = (any == 0) ? 1 : 0;
}

// ---------------------------------------------------------------- hyp_bias = proj(expmap0(bias))
__global__ __launch_bounds__(64) void biask(const float* __restrict__ bias,
                                            const float* __restrict__ attw,
                                            float* __restrict__ hb,
                                            float* __restrict__ hbsc) {
    int t = threadIdx.x;
    float b0 = bias[t], b1 = bias[t + 64];
    float n2 = wsum(b0 * b0 + b1 * b1);
    float n  = fmaxf(sqrtf(n2), 1e-15f);
    float th = tanhf(n);
    float sc = th / n;           // expmap0 scale
    float nn = th;               // resulting norm
    if (nn > 0.996f) { sc *= 0.996f / nn; nn = 0.996f; }
    float h0 = sc * b0, h1 = sc * b1;
    hb[t] = h0; hb[t + 64] = h1;
    float s1 = wsum(attw[t] * h0 + attw[t + 64] * h1);
    float s2 = wsum(attw[128 + t] * h0 + attw[192 + t] * h1);
    if (t == 0) { hbsc[0] = nn * nn; hbsc[1] = s1; hbsc[2] = s2; }
}

// ---------------------------------------------------------------- phase 1: per-node linear + logmap0
// one wave per 8 nodes; lane t owns components t and t+64
__global__ __launch_bounds__(64) void phase1(const float* __restrict__ x,
                                             const float* __restrict__ W,
                                             const float* __restrict__ attw,
                                             const float* __restrict__ hb,
                                             const float* __restrict__ hbsc,
                                             float* __restrict__ xt,
                                             float* __restrict__ a1o,
                                             float* __restrict__ a2o,
                                             int N) {
    const int t = threadIdx.x;
    const int node0 = blockIdx.x * 8;
    int nmax = N - node0; if (nmax > 8) nmax = 8;

    const float w1A = attw[t],       w1B = attw[64 + t];
    const float w2A = attw[128 + t], w2B = attw[192 + t];
    const float hbA = hb[t],         hbB = hb[64 + t];
    const float hb2 = hbsc[0], s1 = hbsc[1], s2 = hbsc[2];

    float acc0[8], acc1[8];
#pragma unroll
    for (int n = 0; n < 8; ++n) { acc0[n] = 0.f; acc1[n] = 0.f; }

    const float* Wr0 = W + (size_t)t * D;
    const float* Wr1 = W + (size_t)(t + 64) * D;

    for (int k = 0; k < D; k += 4) {
        float4 w0 = *(const float4*)(Wr0 + k);
        float4 w1 = *(const float4*)(Wr1 + k);
#pragma unroll
        for (int n = 0; n < 8; ++n) {
            if (n < nmax) {
                float4 xv = *(const float4*)(x + (size_t)(node0 + n) * D + k); // wave-uniform
                acc0[n] = fmaf(w0.x, xv.x, fmaf(w0.y, xv.y, fmaf(w0.z, xv.z, fmaf(w0.w, xv.w, acc0[n]))));
                acc1[n] = fmaf(w1.x, xv.x, fmaf(w1.y, xv.y, fmaf(w1.z, xv.z, fmaf(w1.w, xv.w, acc1[n]))));
            }
        }
    }

    for (int n = 0; n < 8; ++n) {
        if (n >= nmax) break;
        const int i = node0 + n;
        float xa = x[(size_t)i * D + t], xb = x[(size_t)i * D + 64 + t];
        float xn2  = wsum(xa * xa + xb * xb);
        float m0 = acc0[n], m1 = acc1[n];
        float mxn2 = wsum(m0 * m0 + m1 * m1);
        float dmb  = wsum(m0 * hbA + m1 * hbB);
        float r1   = wsum(m0 * w1A + m1 * w1B);
        float r2   = wsum(m0 * w2A + m1 * w2B);

        float xn  = fmaxf(sqrtf(xn2), 1e-15f);
        float mxn = fmaxf(sqrtf(mxn2), 1e-15f);
        float art = atanhf(fminf(xn, 1.f - 1e-7f));
        float th  = tanhf(mxn / xn * art);
        float hnorm = fminf(th, 0.996f);              // proj(mobius_matvec)
        float alpha = hnorm / mxn;                    // h = alpha*mx
        // mobius_add(h, hyp_bias)
        float x2 = hnorm * hnorm, y2 = hb2, xy = alpha * dmb;
        float den = fmaxf(1.f + 2.f * xy + x2 * y2, 1e-15f);
        float cA = (1.f + 2.f * xy + y2) / den * alpha;
        float cB = (1.f - x2) / den;
        float h2n2 = cA * cA * mxn2 + 2.f * cA * cB * dmb + cB * cB * hb2;
        float h2n = fmaxf(sqrtf(h2n2), 1e-15f);
        if (h2n > 0.996f) { float s = 0.996f / h2n; cA *= s; cB *= s; h2n = 0.996f; }
        // logmap0
        float g = atanhf(fminf(h2n, 1.f - 1e-7f)) / h2n;
        cA *= g; cB *= g;

        xt[(size_t)i * D + t]      = cA * m0 + cB * hbA;
        xt[(size_t)i * D + 64 + t] = cA * m1 + cB * hbB;
        if (t == 0) {
            a1o[i] = cA * r1 + cB * s1;
            a2o[i] = cA * r2 + cB * s2;
        }
    }
}

// ---------------------------------------------------------------- edge scatter phase
__global__ __launch_bounds__(256) void edgek(const int* __restrict__ adj,
                                             const float* __restrict__ ea,
                                             const float* __restrict__ attw,
                                             const float* __restrict__ a2,
                                             float* __restrict__ sum_r,
                                             float* __restrict__ sum_c,
                                             float* __restrict__ S2,
                                             float* __restrict__ cnt_r,
                                             float* __restrict__ cnt_c,
                                             const int* __restrict__ flag,
                                             int E) {
    const int lane = threadIdx.x & 63;
    const int wid  = (blockIdx.x * blockDim.x + threadIdx.x) >> 6;
    const int nw   = (gridDim.x * blockDim.x) >> 6;
    const int is64 = *flag;
    const float2 w3 = *(const float2*)(attw + 256 + 2 * lane);

    for (int e = wid; e < E; e += nw) {
        int r, c;
        if (is64) { r = adj[(size_t)2 * e]; c = adj[2 * ((size_t)E + e)]; }
        else      { r = adj[e];             c = adj[(size_t)E + e]; }
        float2 v = *(const float2*)(ea + (size_t)e * D + 2 * lane);
        float d3 = wsum(v.x * w3.x + v.y * w3.y);

        float* pr = sum_r + (size_t)r * D + 2 * lane;
        atomAddF(pr,     v.x);
        atomAddF(pr + 1, v.y);
        float* pc = sum_c + (size_t)c * D + 2 * lane;
        atomAddF(pc,     v.x);
        atomAddF(pc + 1, v.y);
        if (lane == 0) {
            atomAddF(&S2[r], a2[c] + d3);
            atomAddF(&cnt_r[r], 1.f);
            atomAddF(&cnt_c[c], 1.f);
        }
    }
}

// ---------------------------------------------------------------- phase 3: combine + expmap/relu chain
__global__ __launch_bounds__(256) void phase3(const float* __restrict__ xt,
                                              const float* __restrict__ a1,
                                              const float* __restrict__ S2,
                                              const float* __restrict__ cnt_r,
                                              const float* __restrict__ cnt_c,
                                              const float* __restrict__ sum_r,
                                              const float* __restrict__ sum_c,
                                              const float* __restrict__ attb,
                                              float* __restrict__ out,
                                              int N) {
    const int lane = threadIdx.x & 63;
    const int i = (blockIdx.x * blockDim.x + threadIdx.x) >> 6;
    if (i >= N) return;

    float cr = cnt_r[i], cc = cnt_c[i];
    float satt = cr * (a1[i] + attb[0]) + S2[i];   // sum of att over out-edges
    float mr = 1.f / fmaxf(cr, 1.f);
    float mc = 1.f / fmaxf(cc, 1.f);

    float2 xv = *(const float2*)(xt   + (size_t)i * D + 2 * lane);
    float2 sr = *(const float2*)(sum_r + (size_t)i * D + 2 * lane);
    float2 sc = *(const float2*)(sum_c + (size_t)i * D + 2 * lane);
    float s0 = fmaf(xv.x, satt, xv.x) + sr.x * mr + sc.x * mc;
    float s1 = fmaf(xv.y, satt, xv.y) + sr.y * mr + sc.y * mc;

    // proj(expmap0(support))
    float n1 = fmaxf(sqrtf(wsum(s0 * s0 + s1 * s1)), 1e-15f);
    float th1 = tanhf(n1);
    float nrm1 = fminf(th1, 0.996f);
    float sc1 = nrm1 / n1;
    // relu(logmap0(.))
    float lam = atanhf(fminf(nrm1, 1.f - 1e-7f)) / nrm1 * sc1;
    float t0 = fmaxf(lam * s0, 0.f);
    float t1 = fmaxf(lam * s1, 0.f);
    // proj(expmap0(t))
    float n2 = fmaxf(sqrtf(wsum(t0 * t0 + t1 * t1)), 1e-15f);
    float th2 = tanhf(n2);
    float sc2 = fminf(th2, 0.996f) / n2;

    float2 o; o.x = sc2 * t0; o.y = sc2 * t1;
    *(float2*)(out + (size_t)i * D + 2 * lane) = o;
}

// ----------------------------------------------------------------
extern "C" void kernel_launch(void* const* d_in, const int* in_sizes, int n_in,
                              void* d_out, int out_size, void* d_ws, size_t ws_size,
                              hipStream_t stream) {
    const float* x    = (const float*)d_in[0];
    const int*   adj  = (const int*)d_in[1];
    const float* ea   = (const float*)d_in[2];
    const float* W    = (const float*)d_in[3];
    const float* bias = (const float*)d_in[4];
    const float* attw = (const float*)d_in[5];
    const float* attb = (const float*)d_in[6];
    float* out = (float*)d_out;

    const int N = in_sizes[0] / D;   // 50000
    const int E = in_sizes[2] / D;   // 800000

    float* ws = (float*)d_ws;
    float* xt   = ws;  ws += (size_t)N * D;
    float* a1   = ws;  ws += N;
    float* a2   = ws;  ws += N;
    float* hb   = ws;  ws += D;
    float* hbsc = ws;  ws += 4;
    int*   flag = (int*)ws; ws += 4;
    float* zbase = ws;
    float* sum_r = ws; ws += (size_t)N * D;
    float* sum_c = ws; ws += (size_t)N * D;
    float* S2    = ws; ws += N;
    float* cnt_r = ws; ws += N;
    float* cnt_c = ws; ws += N;
    size_t zbytes = (size_t)(ws - zbase) * sizeof(float);

    hipMemsetAsync(zbase, 0, zbytes, stream);
    detectk<<<1, 1, 0, stream>>>(adj, flag);
    biask<<<1, 64, 0, stream>>>(bias, attw, hb, hbsc);
    phase1<<<(N + 7) / 8, 64, 0, stream>>>(x, W, attw, hb, hbsc, xt, a1, a2, N);
    edgek<<<4096, 256, 0, stream>>>(adj, ea, attw, a2, sum_r, sum_c, S2, cnt_r, cnt_c, flag, E);
    phase3<<<(N * 64 + 255) / 256, 256, 0, stream>>>(xt, a1, S2, cnt_r, cnt_c, sum_r, sum_c, attb, out, N);
}

// Round 2
// 660.800 us; speedup vs baseline: 2.6777x; 2.6777x over previous
//
#include <hip/hip_runtime.h>
#include <math.h>

#define D 128

__device__ __forceinline__ float wsum(float v) {
    v += __shfl_xor(v, 1, 64);
    v += __shfl_xor(v, 2, 64);
    v += __shfl_xor(v, 4, 64);
    v += __shfl_xor(v, 8, 64);
    v += __shfl_xor(v, 16, 64);
    v += __shfl_xor(v, 32, 64);
    return v;
}

// ---------------------------------------------------------------- detect adj dtype
__global__ void detectk(const int* __restrict__ adj, int* __restrict__ flag) {
    int any = 0;
    for (int i = 0; i < 64; ++i) any |= adj[2 * i + 1];
    *flag = (any == 0) ? 1 : 0;
}

// ---------------------------------------------------------------- hyp_bias = proj(expmap0(bias))
__global__ __launch_bounds__(64) void biask(const float* __restrict__ bias,
                                            const float* __restrict__ attw,
                                            float* __restrict__ hb,
                                            float* __restrict__ hbsc) {
    int t = threadIdx.x;
    float b0 = bias[t], b1 = bias[t + 64];
    float n2 = wsum(b0 * b0 + b1 * b1);
    float n  = fmaxf(sqrtf(n2), 1e-15f);
    float th = tanhf(n);
    float sc = th / n;
    float nn = th;
    if (nn > 0.996f) { sc *= 0.996f / nn; nn = 0.996f; }
    float h0 = sc * b0, h1 = sc * b1;
    hb[t] = h0; hb[t + 64] = h1;
    float s1 = wsum(attw[t] * h0 + attw[t + 64] * h1);
    float s2 = wsum(attw[128 + t] * h0 + attw[192 + t] * h1);
    if (t == 0) { hbsc[0] = nn * nn; hbsc[1] = s1; hbsc[2] = s2; }
}

// ---------------------------------------------------------------- phase 1: per-node linear + logmap0
__global__ __launch_bounds__(64) void phase1(const float* __restrict__ x,
                                             const float* __restrict__ W,
                                             const float* __restrict__ attw,
                                             const float* __restrict__ hb,
                                             const float* __restrict__ hbsc,
                                             float* __restrict__ xt,
                                             float* __restrict__ a1o,
                                             float* __restrict__ a2o,
                                             int N) {
    const int t = threadIdx.x;
    const int node0 = blockIdx.x * 8;
    int nmax = N - node0; if (nmax > 8) nmax = 8;

    const float w1A = attw[t],       w1B = attw[64 + t];
    const float w2A = attw[128 + t], w2B = attw[192 + t];
    const float hbA = hb[t],         hbB = hb[64 + t];
    const float hb2 = hbsc[0], s1 = hbsc[1], s2 = hbsc[2];

    float acc0[8], acc1[8];
#pragma unroll
    for (int n = 0; n < 8; ++n) { acc0[n] = 0.f; acc1[n] = 0.f; }

    const float* Wr0 = W + (size_t)t * D;
    const float* Wr1 = W + (size_t)(t + 64) * D;

    for (int k = 0; k < D; k += 4) {
        float4 w0 = *(const float4*)(Wr0 + k);
        float4 w1 = *(const float4*)(Wr1 + k);
#pragma unroll
        for (int n = 0; n < 8; ++n) {
            if (n < nmax) {
                float4 xv = *(const float4*)(x + (size_t)(node0 + n) * D + k);
                acc0[n] = fmaf(w0.x, xv.x, fmaf(w0.y, xv.y, fmaf(w0.z, xv.z, fmaf(w0.w, xv.w, acc0[n]))));
                acc1[n] = fmaf(w1.x, xv.x, fmaf(w1.y, xv.y, fmaf(w1.z, xv.z, fmaf(w1.w, xv.w, acc1[n]))));
            }
        }
    }

    for (int n = 0; n < 8; ++n) {
        if (n >= nmax) break;
        const int i = node0 + n;
        float xa = x[(size_t)i * D + t], xb = x[(size_t)i * D + 64 + t];
        float xn2  = wsum(xa * xa + xb * xb);
        float m0 = acc0[n], m1 = acc1[n];
        float mxn2 = wsum(m0 * m0 + m1 * m1);
        float dmb  = wsum(m0 * hbA + m1 * hbB);
        float r1   = wsum(m0 * w1A + m1 * w1B);
        float r2   = wsum(m0 * w2A + m1 * w2B);

        float xn  = fmaxf(sqrtf(xn2), 1e-15f);
        float mxn = fmaxf(sqrtf(mxn2), 1e-15f);
        float art = atanhf(fminf(xn, 1.f - 1e-7f));
        float th  = tanhf(mxn / xn * art);
        float hnorm = fminf(th, 0.996f);
        float alpha = hnorm / mxn;
        float x2 = hnorm * hnorm, y2 = hb2, xy = alpha * dmb;
        float den = fmaxf(1.f + 2.f * xy + x2 * y2, 1e-15f);
        float cA = (1.f + 2.f * xy + y2) / den * alpha;
        float cB = (1.f - x2) / den;
        float h2n2 = cA * cA * mxn2 + 2.f * cA * cB * dmb + cB * cB * hb2;
        float h2n = fmaxf(sqrtf(h2n2), 1e-15f);
        if (h2n > 0.996f) { float s = 0.996f / h2n; cA *= s; cB *= s; h2n = 0.996f; }
        float g = atanhf(fminf(h2n, 1.f - 1e-7f)) / h2n;
        cA *= g; cB *= g;

        xt[(size_t)i * D + t]      = cA * m0 + cB * hbA;
        xt[(size_t)i * D + 64 + t] = cA * m1 + cB * hbB;
        if (t == 0) {
            a1o[i] = cA * r1 + cB * s1;
            a2o[i] = cA * r2 + cB * s2;
        }
    }
}

// ---------------------------------------------------------------- CSR build: degree count
__global__ __launch_bounds__(256) void countk(const int* __restrict__ adj,
                                              int* __restrict__ cnt_r,
                                              int* __restrict__ cnt_c,
                                              const int* __restrict__ flag,
                                              int E) {
    int e = blockIdx.x * blockDim.x + threadIdx.x;
    if (e >= E) return;
    int r, c;
    if (*flag) { r = adj[(size_t)2 * e]; c = adj[2 * ((size_t)E + e)]; }
    else       { r = adj[e];             c = adj[(size_t)E + e]; }
    atomicAdd(&cnt_r[r], 1);
    atomicAdd(&cnt_c[c], 1);
}

// ---------------------------------------------------------------- exclusive scan (one block per array)
__global__ __launch_bounds__(1024) void scank(const int* __restrict__ cnt_r,
                                              const int* __restrict__ cnt_c,
                                              int* __restrict__ start_r,
                                              int* __restrict__ start_c,
                                              int* __restrict__ cur_r,
                                              int* __restrict__ cur_c,
                                              int N) {
    const int* cnt  = blockIdx.x == 0 ? cnt_r : cnt_c;
    int* start      = blockIdx.x == 0 ? start_r : start_c;
    int* cur        = blockIdx.x == 0 ? cur_r : cur_c;
    const int t = threadIdx.x;
    const int NT = 1024;
    const int CH = (N + NT - 1) / NT;
    const int lo = t * CH;
    int hi = lo + CH; if (hi > N) hi = N;

    int local = 0;
    for (int i = lo; i < hi; ++i) local += cnt[i];

    __shared__ int sm[1024];
    sm[t] = local;
    __syncthreads();
    for (int off = 1; off < 1024; off <<= 1) {
        int v = (t >= off) ? sm[t - off] : 0;
        __syncthreads();
        sm[t] += v;
        __syncthreads();
    }
    int run = sm[t] - local;   // exclusive base
    for (int i = lo; i < hi; ++i) {
        start[i] = run;
        cur[i] = run;
        run += cnt[i];
    }
    if (t == NT - 1) start[N] = sm[NT - 1];
}

// ---------------------------------------------------------------- CSR fill
__global__ __launch_bounds__(256) void fillk(const int* __restrict__ adj,
                                             int* __restrict__ cur_r,
                                             int* __restrict__ cur_c,
                                             int* __restrict__ row_edges,
                                             int* __restrict__ col_edges,
                                             const int* __restrict__ flag,
                                             int E) {
    int e = blockIdx.x * blockDim.x + threadIdx.x;
    if (e >= E) return;
    int r, c;
    if (*flag) { r = adj[(size_t)2 * e]; c = adj[2 * ((size_t)E + e)]; }
    else       { r = adj[e];             c = adj[(size_t)E + e]; }
    int p = atomicAdd(&cur_r[r], 1);
    row_edges[p] = e;
    int q = atomicAdd(&cur_c[c], 1);
    col_edges[q] = e;
}

// ---------------------------------------------------------------- fused gather + phase 3
// one wave per node; lane l owns components 2l, 2l+1
__global__ __launch_bounds__(256) void gatherk(const int* __restrict__ adj,
                                               const float* __restrict__ ea,
                                               const float* __restrict__ attw,
                                               const float* __restrict__ attb,
                                               const float* __restrict__ xt,
                                               const float* __restrict__ a1,
                                               const float* __restrict__ a2,
                                               const int* __restrict__ start_r,
                                               const int* __restrict__ start_c,
                                               const int* __restrict__ row_edges,
                                               const int* __restrict__ col_edges,
                                               const int* __restrict__ flag,
                                               float* __restrict__ out,
                                               int N, int E) {
    const int lane = threadIdx.x & 63;
    const int node = (blockIdx.x * blockDim.x + threadIdx.x) >> 6;
    if (node >= N) return;
    const int is64 = *flag;

    const int rs = start_r[node], re = start_r[node + 1];
    const int cs = start_c[node], ce = start_c[node + 1];

    float2 accr = {0.f, 0.f}, accc = {0.f, 0.f};

    // out-edge (row) gather, unroll 2 for load ILP
    int j = rs;
    for (; j + 1 < re; j += 2) {
        int e0 = row_edges[j], e1 = row_edges[j + 1];
        float2 v0 = *(const float2*)(ea + (size_t)e0 * D + 2 * lane);
        float2 v1 = *(const float2*)(ea + (size_t)e1 * D + 2 * lane);
        accr.x += v0.x + v1.x; accr.y += v0.y + v1.y;
    }
    if (j < re) {
        int e0 = row_edges[j];
        float2 v0 = *(const float2*)(ea + (size_t)e0 * D + 2 * lane);
        accr.x += v0.x; accr.y += v0.y;
    }

    // in-edge (col) gather
    j = cs;
    for (; j + 1 < ce; j += 2) {
        int e0 = col_edges[j], e1 = col_edges[j + 1];
        float2 v0 = *(const float2*)(ea + (size_t)e0 * D + 2 * lane);
        float2 v1 = *(const float2*)(ea + (size_t)e1 * D + 2 * lane);
        accc.x += v0.x + v1.x; accc.y += v0.y + v1.y;
    }
    if (j < ce) {
        int e0 = col_edges[j];
        float2 v0 = *(const float2*)(ea + (size_t)e0 * D + 2 * lane);
        accc.x += v0.x; accc.y += v0.y;
    }

    // sum of a2[col(e)] over out-edges (lane-parallel)
    float s = 0.f;
    for (int k = rs + lane; k < re; k += 64) {
        int e = row_edges[k];
        int c = is64 ? adj[2 * ((size_t)E + e)] : adj[(size_t)E + e];
        s += a2[c];
    }
    s = wsum(s);

    // d3 total via linearity: dot(w3, sum_out ea)
    float2 w3 = *(const float2*)(attw + 256 + 2 * lane);
    float d3 = wsum(accr.x * w3.x + accr.y * w3.y);

    float degr = (float)(re - rs), degc = (float)(ce - cs);
    float satt = degr * (a1[node] + attb[0]) + s + d3;
    float mr = 1.f / fmaxf(degr, 1.f);
    float mc = 1.f / fmaxf(degc, 1.f);

    float2 xv = *(const float2*)(xt + (size_t)node * D + 2 * lane);
    float s0 = fmaf(xv.x, satt, xv.x) + accr.x * mr + accc.x * mc;
    float s1 = fmaf(xv.y, satt, xv.y) + accr.y * mr + accc.y * mc;

    // proj(expmap0(support))
    float n1 = fmaxf(sqrtf(wsum(s0 * s0 + s1 * s1)), 1e-15f);
    float th1 = tanhf(n1);
    float nrm1 = fminf(th1, 0.996f);
    float sc1 = nrm1 / n1;
    // relu(logmap0(.))
    float lam = atanhf(fminf(nrm1, 1.f - 1e-7f)) / nrm1 * sc1;
    float t0 = fmaxf(lam * s0, 0.f);
    float t1 = fmaxf(lam * s1, 0.f);
    // proj(expmap0(t))
    float n2 = fmaxf(sqrtf(wsum(t0 * t0 + t1 * t1)), 1e-15f);
    float th2 = tanhf(n2);
    float sc2 = fminf(th2, 0.996f) / n2;

    float2 o; o.x = sc2 * t0; o.y = sc2 * t1;
    *(float2*)(out + (size_t)node * D + 2 * lane) = o;
}

// ----------------------------------------------------------------
extern "C" void kernel_launch(void* const* d_in, const int* in_sizes, int n_in,
                              void* d_out, int out_size, void* d_ws, size_t ws_size,
                              hipStream_t stream) {
    const float* x    = (const float*)d_in[0];
    const int*   adj  = (const int*)d_in[1];
    const float* ea   = (const float*)d_in[2];
    const float* W    = (const float*)d_in[3];
    const float* bias = (const float*)d_in[4];
    const float* attw = (const float*)d_in[5];
    const float* attb = (const float*)d_in[6];
    float* out = (float*)d_out;

    const int N = in_sizes[0] / D;   // 50000
    const int E = in_sizes[2] / D;   // 800000

    float* ws = (float*)d_ws;
    float* xt   = ws;  ws += (size_t)N * D;
    float* a1   = ws;  ws += N;
    float* a2   = ws;  ws += N;
    float* hb   = ws;  ws += D;
    float* hbsc = ws;  ws += 4;
    int*   flag = (int*)ws; ws += 4;
    int* iws = (int*)ws;
    int* cnt_r   = iws;  iws += N;
    int* cnt_c   = iws;  iws += N;
    int* start_r = iws;  iws += N + 1;
    int* start_c = iws;  iws += N + 1;
    int* cur_r   = iws;  iws += N;
    int* cur_c   = iws;  iws += N;
    int* row_edges = iws; iws += E;
    int* col_edges = iws; iws += E;

    hipMemsetAsync(cnt_r, 0, 2 * (size_t)N * sizeof(int), stream);
    detectk<<<1, 1, 0, stream>>>(adj, flag);
    biask<<<1, 64, 0, stream>>>(bias, attw, hb, hbsc);
    phase1<<<(N + 7) / 8, 64, 0, stream>>>(x, W, attw, hb, hbsc, xt, a1, a2, N);
    countk<<<(E + 255) / 256, 256, 0, stream>>>(adj, cnt_r, cnt_c, flag, E);
    scank<<<2, 1024, 0, stream>>>(cnt_r, cnt_c, start_r, start_c, cur_r, cur_c, N);
    fillk<<<(E + 255) / 256, 256, 0, stream>>>(adj, cur_r, cur_c, row_edges, col_edges, flag, E);
    gatherk<<<(N * 64 + 255) / 256, 256, 0, stream>>>(adj, ea, attw, attb, xt, a1, a2,
                                                      start_r, start_c, row_edges, col_edges,
                                                      flag, out, N, E);
}

// Round 3
// 635.412 us; speedup vs baseline: 2.7847x; 1.0400x over previous
//
#include <hip/hip_runtime.h>
#include <math.h>

#define D 128

__device__ __forceinline__ float wsum(float v) {
    v += __shfl_xor(v, 1, 64);
    v += __shfl_xor(v, 2, 64);
    v += __shfl_xor(v, 4, 64);
    v += __shfl_xor(v, 8, 64);
    v += __shfl_xor(v, 16, 64);
    v += __shfl_xor(v, 32, 64);
    return v;
}

__device__ __forceinline__ float4 ld4(const float* p) { return *(const float4*)p; }

// ---------------------------------------------------------------- zero int buffer
__global__ __launch_bounds__(256) void zerok(int* __restrict__ p, int n) {
    int i = blockIdx.x * blockDim.x + threadIdx.x;
    if (i < n) p[i] = 0;
}

// ---------------------------------------------------------------- detect adj dtype (wave-parallel)
__global__ __launch_bounds__(64) void detectk(const int* __restrict__ adj, int* __restrict__ flag) {
    int v = adj[2 * threadIdx.x + 1];
    unsigned long long m = __ballot(v != 0);
    if (threadIdx.x == 0) *flag = (m == 0ULL) ? 1 : 0;
}

// ---------------------------------------------------------------- hyp_bias = proj(expmap0(bias))
__global__ __launch_bounds__(64) void biask(const float* __restrict__ bias,
                                            const float* __restrict__ attw,
                                            float* __restrict__ hb,
                                            float* __restrict__ hbsc) {
    int t = threadIdx.x;
    float b0 = bias[t], b1 = bias[t + 64];
    float n2 = wsum(b0 * b0 + b1 * b1);
    float n  = fmaxf(sqrtf(n2), 1e-15f);
    float th = tanhf(n);
    float sc = th / n;
    float nn = th;
    if (nn > 0.996f) { sc *= 0.996f / nn; nn = 0.996f; }
    float h0 = sc * b0, h1 = sc * b1;
    hb[t] = h0; hb[t + 64] = h1;
    float s1 = wsum(attw[t] * h0 + attw[t + 64] * h1);
    float s2 = wsum(attw[128 + t] * h0 + attw[192 + t] * h1);
    if (t == 0) { hbsc[0] = nn * nn; hbsc[1] = s1; hbsc[2] = s2; }
}

// ---------------------------------------------------------------- phase 1: per-node linear + logmap0
__global__ __launch_bounds__(64) void phase1(const float* __restrict__ x,
                                             const float* __restrict__ W,
                                             const float* __restrict__ attw,
                                             const float* __restrict__ hb,
                                             const float* __restrict__ hbsc,
                                             float* __restrict__ xt,
                                             float* __restrict__ a1o,
                                             float* __restrict__ a2o,
                                             int N) {
    const int t = threadIdx.x;
    const int node0 = blockIdx.x * 8;
    int nmax = N - node0; if (nmax > 8) nmax = 8;

    const float w1A = attw[t],       w1B = attw[64 + t];
    const float w2A = attw[128 + t], w2B = attw[192 + t];
    const float hbA = hb[t],         hbB = hb[64 + t];
    const float hb2 = hbsc[0], s1 = hbsc[1], s2 = hbsc[2];

    float acc0[8], acc1[8];
#pragma unroll
    for (int n = 0; n < 8; ++n) { acc0[n] = 0.f; acc1[n] = 0.f; }

    const float* Wr0 = W + (size_t)t * D;
    const float* Wr1 = W + (size_t)(t + 64) * D;

    for (int k = 0; k < D; k += 4) {
        float4 w0 = ld4(Wr0 + k);
        float4 w1 = ld4(Wr1 + k);
#pragma unroll
        for (int n = 0; n < 8; ++n) {
            if (n < nmax) {
                float4 xv = ld4(x + (size_t)(node0 + n) * D + k);
                acc0[n] = fmaf(w0.x, xv.x, fmaf(w0.y, xv.y, fmaf(w0.z, xv.z, fmaf(w0.w, xv.w, acc0[n]))));
                acc1[n] = fmaf(w1.x, xv.x, fmaf(w1.y, xv.y, fmaf(w1.z, xv.z, fmaf(w1.w, xv.w, acc1[n]))));
            }
        }
    }

    for (int n = 0; n < 8; ++n) {
        if (n >= nmax) break;
        const int i = node0 + n;
        float xa = x[(size_t)i * D + t], xb = x[(size_t)i * D + 64 + t];
        float xn2  = wsum(xa * xa + xb * xb);
        float m0 = acc0[n], m1 = acc1[n];
        float mxn2 = wsum(m0 * m0 + m1 * m1);
        float dmb  = wsum(m0 * hbA + m1 * hbB);
        float r1   = wsum(m0 * w1A + m1 * w1B);
        float r2   = wsum(m0 * w2A + m1 * w2B);

        float xn  = fmaxf(sqrtf(xn2), 1e-15f);
        float mxn = fmaxf(sqrtf(mxn2), 1e-15f);
        float art = atanhf(fminf(xn, 1.f - 1e-7f));
        float th  = tanhf(mxn / xn * art);
        float hnorm = fminf(th, 0.996f);
        float alpha = hnorm / mxn;
        float x2 = hnorm * hnorm, y2 = hb2, xy = alpha * dmb;
        float den = fmaxf(1.f + 2.f * xy + x2 * y2, 1e-15f);
        float cA = (1.f + 2.f * xy + y2) / den * alpha;
        float cB = (1.f - x2) / den;
        float h2n2 = cA * cA * mxn2 + 2.f * cA * cB * dmb + cB * cB * hb2;
        float h2n = fmaxf(sqrtf(h2n2), 1e-15f);
        if (h2n > 0.996f) { float s = 0.996f / h2n; cA *= s; cB *= s; h2n = 0.996f; }
        float g = atanhf(fminf(h2n, 1.f - 1e-7f)) / h2n;
        cA *= g; cB *= g;

        xt[(size_t)i * D + t]      = cA * m0 + cB * hbA;
        xt[(size_t)i * D + 64 + t] = cA * m1 + cB * hbB;
        if (t == 0) {
            a1o[i] = cA * r1 + cB * s1;
            a2o[i] = cA * r2 + cB * s2;
        }
    }
}

// ---------------------------------------------------------------- CSR build: degree count
__global__ __launch_bounds__(256) void countk(const int* __restrict__ adj,
                                              int* __restrict__ cnt_r,
                                              int* __restrict__ cnt_c,
                                              const int* __restrict__ flag,
                                              int E) {
    int e = blockIdx.x * blockDim.x + threadIdx.x;
    if (e >= E) return;
    int r, c;
    if (*flag) { r = adj[(size_t)2 * e]; c = adj[2 * ((size_t)E + e)]; }
    else       { r = adj[e];             c = adj[(size_t)E + e]; }
    atomicAdd(&cnt_r[r], 1);
    atomicAdd(&cnt_c[c], 1);
}

// ---------------------------------------------------------------- exclusive scan (one block per array)
__global__ __launch_bounds__(1024) void scank(const int* __restrict__ cnt_r,
                                              const int* __restrict__ cnt_c,
                                              int* __restrict__ start_r,
                                              int* __restrict__ start_c,
                                              int* __restrict__ cur_r,
                                              int* __restrict__ cur_c,
                                              int N) {
    const int* cnt  = blockIdx.x == 0 ? cnt_r : cnt_c;
    int* start      = blockIdx.x == 0 ? start_r : start_c;
    int* cur        = blockIdx.x == 0 ? cur_r : cur_c;
    const int t = threadIdx.x;
    const int NT = 1024;
    const int CH = (N + NT - 1) / NT;
    const int lo = t * CH;
    int hi = lo + CH; if (hi > N) hi = N;

    int local = 0;
    for (int i = lo; i < hi; ++i) local += cnt[i];

    __shared__ int sm[1024];
    sm[t] = local;
    __syncthreads();
    for (int off = 1; off < 1024; off <<= 1) {
        int v = (t >= off) ? sm[t - off] : 0;
        __syncthreads();
        sm[t] += v;
        __syncthreads();
    }
    int run = sm[t] - local;
    for (int i = lo; i < hi; ++i) {
        start[i] = run;
        cur[i] = run;
        run += cnt[i];
    }
    if (t == NT - 1) start[N] = sm[NT - 1];
}

// ---------------------------------------------------------------- CSR fill (+ a2[col] staged into row-CSR order)
__global__ __launch_bounds__(256) void fillk(const int* __restrict__ adj,
                                             const float* __restrict__ a2,
                                             int* __restrict__ cur_r,
                                             int* __restrict__ cur_c,
                                             int* __restrict__ row_edges,
                                             float* __restrict__ row_a2,
                                             int* __restrict__ col_edges,
                                             const int* __restrict__ flag,
                                             int E) {
    int e = blockIdx.x * blockDim.x + threadIdx.x;
    if (e >= E) return;
    int r, c;
    if (*flag) { r = adj[(size_t)2 * e]; c = adj[2 * ((size_t)E + e)]; }
    else       { r = adj[e];             c = adj[(size_t)E + e]; }
    int p = atomicAdd(&cur_r[r], 1);
    row_edges[p] = e;
    row_a2[p]    = a2[c];           // a2 is 200 KB -> L2-resident random read
    int q = atomicAdd(&cur_c[c], 1);
    col_edges[q] = e;
}

// ---------------------------------------------------------------- fused gather + phase 3
// one wave per node; 2 edges per iteration (half-wave each, float4 lanes)
__global__ __launch_bounds__(256) void gatherk(const float* __restrict__ ea,
                                               const float* __restrict__ attw,
                                               const float* __restrict__ attb,
                                               const float* __restrict__ xt,
                                               const float* __restrict__ a1,
                                               const int* __restrict__ start_r,
                                               const int* __restrict__ start_c,
                                               const int* __restrict__ row_edges,
                                               const float* __restrict__ row_a2,
                                               const int* __restrict__ col_edges,
                                               float* __restrict__ out,
                                               int N) {
    const int lane = threadIdx.x & 63;
    const int half = lane >> 5;
    const int l32  = lane & 31;
    const int node = (blockIdx.x * blockDim.x + threadIdx.x) >> 6;
    if (node >= N) return;

    const int rs = start_r[node], re = start_r[node + 1];
    const int cs = start_c[node], ce = start_c[node + 1];

    // ---- out-edge (row) gather of ea
    float4 ar0 = make_float4(0.f, 0.f, 0.f, 0.f), ar1 = ar0;
    int j = rs;
    for (; j + 4 <= re; j += 4) {
        int e0 = row_edges[j + half];
        int e1 = row_edges[j + 2 + half];
        float4 v0 = ld4(ea + (size_t)e0 * D + 4 * l32);
        float4 v1 = ld4(ea + (size_t)e1 * D + 4 * l32);
        ar0.x += v0.x; ar0.y += v0.y; ar0.z += v0.z; ar0.w += v0.w;
        ar1.x += v1.x; ar1.y += v1.y; ar1.z += v1.z; ar1.w += v1.w;
    }
    for (; j + 2 <= re; j += 2) {
        int e0 = row_edges[j + half];
        float4 v0 = ld4(ea + (size_t)e0 * D + 4 * l32);
        ar0.x += v0.x; ar0.y += v0.y; ar0.z += v0.z; ar0.w += v0.w;
    }
    if (j + half < re) {
        int e0 = row_edges[j + half];
        float4 v0 = ld4(ea + (size_t)e0 * D + 4 * l32);
        ar0.x += v0.x; ar0.y += v0.y; ar0.z += v0.z; ar0.w += v0.w;
    }
    float4 ar;
    ar.x = ar0.x + ar1.x; ar.y = ar0.y + ar1.y; ar.z = ar0.z + ar1.z; ar.w = ar0.w + ar1.w;
    ar.x += __shfl_xor(ar.x, 32, 64); ar.y += __shfl_xor(ar.y, 32, 64);
    ar.z += __shfl_xor(ar.z, 32, 64); ar.w += __shfl_xor(ar.w, 32, 64);
    // ar now duplicated across halves: lane holds comps 4*l32 .. 4*l32+3

    // ---- in-edge (col) gather of ea
    float4 ac0 = make_float4(0.f, 0.f, 0.f, 0.f), ac1 = ac0;
    j = cs;
    for (; j + 4 <= ce; j += 4) {
        int e0 = col_edges[j + half];
        int e1 = col_edges[j + 2 + half];
        float4 v0 = ld4(ea + (size_t)e0 * D + 4 * l32);
        float4 v1 = ld4(ea + (size_t)e1 * D + 4 * l32);
        ac0.x += v0.x; ac0.y += v0.y; ac0.z += v0.z; ac0.w += v0.w;
        ac1.x += v1.x; ac1.y += v1.y; ac1.z += v1.z; ac1.w += v1.w;
    }
    for (; j + 2 <= ce; j += 2) {
        int e0 = col_edges[j + half];
        float4 v0 = ld4(ea + (size_t)e0 * D + 4 * l32);
        ac0.x += v0.x; ac0.y += v0.y; ac0.z += v0.z; ac0.w += v0.w;
    }
    if (j + half < ce) {
        int e0 = col_edges[j + half];
        float4 v0 = ld4(ea + (size_t)e0 * D + 4 * l32);
        ac0.x += v0.x; ac0.y += v0.y; ac0.z += v0.z; ac0.w += v0.w;
    }
    float4 ac;
    ac.x = ac0.x + ac1.x; ac.y = ac0.y + ac1.y; ac.z = ac0.z + ac1.z; ac.w = ac0.w + ac1.w;
    ac.x += __shfl_xor(ac.x, 32, 64); ac.y += __shfl_xor(ac.y, 32, 64);
    ac.z += __shfl_xor(ac.z, 32, 64); ac.w += __shfl_xor(ac.w, 32, 64);

    // ---- sum of a2[col(e)] over out-edges (contiguous, all 64 lanes distinct)
    float sp = 0.f;
    for (int k2 = rs + lane; k2 < re; k2 += 64) sp += row_a2[k2];
    float s = wsum(sp);

    // ---- d3 total = dot(w3, sum_out ea)   (duplicated halves -> x0.5)
    float4 w34 = ld4(attw + 256 + 4 * l32);
    float d3 = 0.5f * wsum(ar.x * w34.x + ar.y * w34.y + ar.z * w34.z + ar.w * w34.w);

    float degr = (float)(re - rs), degc = (float)(ce - cs);
    float satt = degr * (a1[node] + attb[0]) + s + d3;
    float mr = 1.f / fmaxf(degr, 1.f);
    float mc = 1.f / fmaxf(degc, 1.f);

    float4 xv = ld4(xt + (size_t)node * D + 4 * l32);
    float4 s4;
    s4.x = fmaf(xv.x, satt, xv.x) + ar.x * mr + ac.x * mc;
    s4.y = fmaf(xv.y, satt, xv.y) + ar.y * mr + ac.y * mc;
    s4.z = fmaf(xv.z, satt, xv.z) + ar.z * mr + ac.z * mc;
    s4.w = fmaf(xv.w, satt, xv.w) + ar.w * mr + ac.w * mc;

    // proj(expmap0(support))   (duplicated halves -> x0.5 on reductions)
    float n1 = fmaxf(sqrtf(0.5f * wsum(s4.x * s4.x + s4.y * s4.y + s4.z * s4.z + s4.w * s4.w)), 1e-15f);
    float th1 = tanhf(n1);
    float nrm1 = fminf(th1, 0.996f);
    float sc1 = nrm1 / n1;
    // relu(logmap0(.))
    float lam = atanhf(fminf(nrm1, 1.f - 1e-7f)) / nrm1 * sc1;
    float4 t4;
    t4.x = fmaxf(lam * s4.x, 0.f); t4.y = fmaxf(lam * s4.y, 0.f);
    t4.z = fmaxf(lam * s4.z, 0.f); t4.w = fmaxf(lam * s4.w, 0.f);
    // proj(expmap0(t))
    float n2 = fmaxf(sqrtf(0.5f * wsum(t4.x * t4.x + t4.y * t4.y + t4.z * t4.z + t4.w * t4.w)), 1e-15f);
    float th2 = tanhf(n2);
    float sc2 = fminf(th2, 0.996f) / n2;

    if (half == 0) {
        float4 o; o.x = sc2 * t4.x; o.y = sc2 * t4.y; o.z = sc2 * t4.z; o.w = sc2 * t4.w;
        *(float4*)(out + (size_t)node * D + 4 * l32) = o;
    }
}

// ----------------------------------------------------------------
extern "C" void kernel_launch(void* const* d_in, const int* in_sizes, int n_in,
                              void* d_out, int out_size, void* d_ws, size_t ws_size,
                              hipStream_t stream) {
    const float* x    = (const float*)d_in[0];
    const int*   adj  = (const int*)d_in[1];
    const float* ea   = (const float*)d_in[2];
    const float* W    = (const float*)d_in[3];
    const float* bias = (const float*)d_in[4];
    const float* attw = (const float*)d_in[5];
    const float* attb = (const float*)d_in[6];
    float* out = (float*)d_out;

    const int N = in_sizes[0] / D;   // 50000
    const int E = in_sizes[2] / D;   // 800000

    float* ws = (float*)d_ws;
    float* xt   = ws;  ws += (size_t)N * D;
    float* a1   = ws;  ws += N;
    float* a2   = ws;  ws += N;
    float* hb   = ws;  ws += D;
    float* hbsc = ws;  ws += 4;
    float* row_a2 = ws; ws += E;
    int* iws = (int*)ws;
    int* flag    = iws;  iws += 4;
    int* cnt_r   = iws;  iws += N;
    int* cnt_c   = iws;  iws += N;
    int* start_r = iws;  iws += N + 1;
    int* start_c = iws;  iws += N + 1;
    int* cur_r   = iws;  iws += N;
    int* cur_c   = iws;  iws += N;
    int* row_edges = iws; iws += E;
    int* col_edges = iws; iws += E;

    zerok<<<(2 * N + 255) / 256, 256, 0, stream>>>(cnt_r, 2 * N);  // cnt_r, cnt_c contiguous
    detectk<<<1, 64, 0, stream>>>(adj, flag);
    biask<<<1, 64, 0, stream>>>(bias, attw, hb, hbsc);
    phase1<<<(N + 7) / 8, 64, 0, stream>>>(x, W, attw, hb, hbsc, xt, a1, a2, N);
    countk<<<(E + 255) / 256, 256, 0, stream>>>(adj, cnt_r, cnt_c, flag, E);
    scank<<<2, 1024, 0, stream>>>(cnt_r, cnt_c, start_r, start_c, cur_r, cur_c, N);
    fillk<<<(E + 255) / 256, 256, 0, stream>>>(adj, a2, cur_r, cur_c, row_edges, row_a2, col_edges, flag, E);
    gatherk<<<(N * 64 + 255) / 256, 256, 0, stream>>>(ea, attw, attb, xt, a1,
                                                      start_r, start_c, row_edges, row_a2, col_edges,
                                                      out, N);
}

// Round 4
// 634.767 us; speedup vs baseline: 2.7875x; 1.0010x over previous
//
#include <hip/hip_runtime.h>
#include <math.h>

#define D 128

__device__ __forceinline__ float wsum(float v) {
    v += __shfl_xor(v, 1, 64);
    v += __shfl_xor(v, 2, 64);
    v += __shfl_xor(v, 4, 64);
    v += __shfl_xor(v, 8, 64);
    v += __shfl_xor(v, 16, 64);
    v += __shfl_xor(v, 32, 64);
    return v;
}

__device__ __forceinline__ float4 ld4(const float* p) { return *(const float4*)p; }

// round-to-nearest-even f32 -> bf16 (manual, exact for normals; inputs are small normals)
__device__ __forceinline__ unsigned int bf16rne(float f) {
    unsigned int u = __float_as_uint(f);
    return (u + 0x7fffu + ((u >> 16) & 1u)) >> 16;
}

// ---------------------------------------------------------------- D1: zero counters + detect dtype + hyp_bias
__global__ __launch_bounds__(256) void initk(const int* __restrict__ adj,
                                             const float* __restrict__ bias,
                                             const float* __restrict__ attw,
                                             int* __restrict__ cnt,   // 2N ints (cnt_r | cnt_c)
                                             int* __restrict__ flag,
                                             float* __restrict__ hb,
                                             float* __restrict__ hbsc,
                                             int n2, int ZB) {
    const int b = blockIdx.x;
    if (b < ZB) {
        int i = b * 256 + threadIdx.x;
        if (i < n2) cnt[i] = 0;
    } else if (b == ZB) {
        if (threadIdx.x < 64) {
            int v = adj[2 * threadIdx.x + 1];
            unsigned long long m = __ballot(v != 0);
            if (threadIdx.x == 0) *flag = (m == 0ULL) ? 1 : 0;
        }
    } else {
        if (threadIdx.x < 64) {
            int t = threadIdx.x;
            float b0 = bias[t], b1 = bias[t + 64];
            float n2f = wsum(b0 * b0 + b1 * b1);
            float n  = fmaxf(sqrtf(n2f), 1e-15f);
            float th = tanhf(n);
            float sc = th / n;
            float nn = th;
            if (nn > 0.996f) { sc *= 0.996f / nn; nn = 0.996f; }
            float h0 = sc * b0, h1 = sc * b1;
            hb[t] = h0; hb[t + 64] = h1;
            float s1 = wsum(attw[t] * h0 + attw[t + 64] * h1);
            float s2 = wsum(attw[128 + t] * h0 + attw[192 + t] * h1);
            if (t == 0) { hbsc[0] = nn * nn; hbsc[1] = s1; hbsc[2] = s2; }
        }
    }
}

// ---------------------------------------------------------------- D2: fused phase1 | count | bf16-convert
__global__ __launch_bounds__(256) void fusedk(const float* __restrict__ x,
                                              const float* __restrict__ W,
                                              const float* __restrict__ attw,
                                              const float* __restrict__ hb,
                                              const float* __restrict__ hbsc,
                                              const int* __restrict__ adj,
                                              const float* __restrict__ ea,
                                              const int* __restrict__ flag,
                                              float* __restrict__ xt,
                                              float* __restrict__ a1o,
                                              float* __restrict__ a2o,
                                              int* __restrict__ cnt_r,
                                              int* __restrict__ cnt_c,
                                              unsigned int* __restrict__ eb,   // E*64 uints (bf16x2)
                                              int N, int E,
                                              int P1B, int CB, int VB) {
    const int b = blockIdx.x;

    if (b < P1B) {
        // ------- phase1 role: 4 waves/block, 8 nodes/wave
        const int t = threadIdx.x & 63;
        const int node0 = b * 32 + (threadIdx.x >> 6) * 8;
        int nmax = N - node0; if (nmax > 8) nmax = 8;
        if (nmax <= 0) return;

        const float w1A = attw[t],       w1B = attw[64 + t];
        const float w2A = attw[128 + t], w2B = attw[192 + t];
        const float hbA = hb[t],         hbB = hb[64 + t];
        const float hb2 = hbsc[0], s1 = hbsc[1], s2 = hbsc[2];

        float acc0[8], acc1[8];
#pragma unroll
        for (int n = 0; n < 8; ++n) { acc0[n] = 0.f; acc1[n] = 0.f; }

        const float* Wr0 = W + (size_t)t * D;
        const float* Wr1 = W + (size_t)(t + 64) * D;

        for (int k = 0; k < D; k += 4) {
            float4 w0 = ld4(Wr0 + k);
            float4 w1 = ld4(Wr1 + k);
#pragma unroll
            for (int n = 0; n < 8; ++n) {
                if (n < nmax) {
                    float4 xv = ld4(x + (size_t)(node0 + n) * D + k);
                    acc0[n] = fmaf(w0.x, xv.x, fmaf(w0.y, xv.y, fmaf(w0.z, xv.z, fmaf(w0.w, xv.w, acc0[n]))));
                    acc1[n] = fmaf(w1.x, xv.x, fmaf(w1.y, xv.y, fmaf(w1.z, xv.z, fmaf(w1.w, xv.w, acc1[n]))));
                }
            }
        }

        for (int n = 0; n < 8; ++n) {
            if (n >= nmax) break;
            const int i = node0 + n;
            float xa = x[(size_t)i * D + t], xb = x[(size_t)i * D + 64 + t];
            float xn2  = wsum(xa * xa + xb * xb);
            float m0 = acc0[n], m1 = acc1[n];
            float mxn2 = wsum(m0 * m0 + m1 * m1);
            float dmb  = wsum(m0 * hbA + m1 * hbB);
            float r1   = wsum(m0 * w1A + m1 * w1B);
            float r2   = wsum(m0 * w2A + m1 * w2B);

            float xn  = fmaxf(sqrtf(xn2), 1e-15f);
            float mxn = fmaxf(sqrtf(mxn2), 1e-15f);
            float art = atanhf(fminf(xn, 1.f - 1e-7f));
            float th  = tanhf(mxn / xn * art);
            float hnorm = fminf(th, 0.996f);
            float alpha = hnorm / mxn;
            float x2 = hnorm * hnorm, y2 = hb2, xy = alpha * dmb;
            float den = fmaxf(1.f + 2.f * xy + x2 * y2, 1e-15f);
            float cA = (1.f + 2.f * xy + y2) / den * alpha;
            float cB = (1.f - x2) / den;
            float h2n2 = cA * cA * mxn2 + 2.f * cA * cB * dmb + cB * cB * hb2;
            float h2n = fmaxf(sqrtf(h2n2), 1e-15f);
            if (h2n > 0.996f) { float s = 0.996f / h2n; cA *= s; cB *= s; h2n = 0.996f; }
            float g = atanhf(fminf(h2n, 1.f - 1e-7f)) / h2n;
            cA *= g; cB *= g;

            xt[(size_t)i * D + t]      = cA * m0 + cB * hbA;
            xt[(size_t)i * D + 64 + t] = cA * m1 + cB * hbB;
            if (t == 0) {
                a1o[i] = cA * r1 + cB * s1;
                a2o[i] = cA * r2 + cB * s2;
            }
        }
    } else if (b < P1B + CB) {
        // ------- count role
        const int is64 = *flag;
        int idx = (b - P1B) * 256 + threadIdx.x;
        const int stride = CB * 256;
        for (int e = idx; e < E; e += stride) {
            int r, c;
            if (is64) { r = adj[(size_t)2 * e]; c = adj[2 * ((size_t)E + e)]; }
            else      { r = adj[e];             c = adj[(size_t)E + e]; }
            atomicAdd(&cnt_r[r], 1);
            atomicAdd(&cnt_c[c], 1);
        }
    } else {
        // ------- bf16 conversion role: float4 -> uint2
        const long long F4 = (long long)E * (D / 4);
        long long idx = (long long)(b - P1B - CB) * 256 + threadIdx.x;
        const long long stride = (long long)VB * 256;
        const float4* ea4 = (const float4*)ea;
        uint2* eb2 = (uint2*)eb;
        for (long long f = idx; f < F4; f += stride) {
            float4 v = ea4[f];
            uint2 o;
            o.x = bf16rne(v.x) | (bf16rne(v.y) << 16);
            o.y = bf16rne(v.z) | (bf16rne(v.w) << 16);
            eb2[f] = o;
        }
    }
}

// ---------------------------------------------------------------- D3: exclusive scan (one block per array)
__global__ __launch_bounds__(1024) void scank(const int* __restrict__ cnt_r,
                                              const int* __restrict__ cnt_c,
                                              int* __restrict__ start_r,
                                              int* __restrict__ start_c,
                                              int* __restrict__ cur_r,
                                              int* __restrict__ cur_c,
                                              int N) {
    const int* cnt  = blockIdx.x == 0 ? cnt_r : cnt_c;
    int* start      = blockIdx.x == 0 ? start_r : start_c;
    int* cur        = blockIdx.x == 0 ? cur_r : cur_c;
    const int t = threadIdx.x;
    const int NT = 1024;
    const int CH = (N + NT - 1) / NT;
    const int lo = t * CH;
    int hi = lo + CH; if (hi > N) hi = N;

    int local = 0;
    for (int i = lo; i < hi; ++i) local += cnt[i];

    __shared__ int sm[1024];
    sm[t] = local;
    __syncthreads();
    for (int off = 1; off < 1024; off <<= 1) {
        int v = (t >= off) ? sm[t - off] : 0;
        __syncthreads();
        sm[t] += v;
        __syncthreads();
    }
    int run = sm[t] - local;
    for (int i = lo; i < hi; ++i) {
        start[i] = run;
        cur[i] = run;
        run += cnt[i];
    }
    if (t == NT - 1) start[N] = sm[NT - 1];
}

// ---------------------------------------------------------------- D4: CSR fill (row side packed with a2[col])
__global__ __launch_bounds__(256) void fillk(const int* __restrict__ adj,
                                             const float* __restrict__ a2,
                                             int* __restrict__ cur_r,
                                             int* __restrict__ cur_c,
                                             int2* __restrict__ row_pairs,
                                             int* __restrict__ col_edges,
                                             const int* __restrict__ flag,
                                             int E) {
    int e = blockIdx.x * blockDim.x + threadIdx.x;
    if (e >= E) return;
    int r, c;
    if (*flag) { r = adj[(size_t)2 * e]; c = adj[2 * ((size_t)E + e)]; }
    else       { r = adj[e];             c = adj[(size_t)E + e]; }
    int p = atomicAdd(&cur_r[r], 1);
    row_pairs[p] = make_int2(e, __float_as_int(a2[c]));
    int q = atomicAdd(&cur_c[c], 1);
    col_edges[q] = e;
}

// ---------------------------------------------------------------- D5: fused gather (bf16) + phase 3
// one wave per node; 2 edges per iteration (half-wave each, 4 comps/lane)
__global__ __launch_bounds__(256) void gatherk(const unsigned int* __restrict__ eb,
                                               const float* __restrict__ attw,
                                               const float* __restrict__ attb,
                                               const float* __restrict__ xt,
                                               const float* __restrict__ a1,
                                               const int* __restrict__ start_r,
                                               const int* __restrict__ start_c,
                                               const int2* __restrict__ row_pairs,
                                               const int* __restrict__ col_edges,
                                               float* __restrict__ out,
                                               int N) {
    const int lane = threadIdx.x & 63;
    const int half = lane >> 5;
    const int l32  = lane & 31;
    const int node = (blockIdx.x * blockDim.x + threadIdx.x) >> 6;
    if (node >= N) return;
    const uint2* eb2 = (const uint2*)eb;   // row e at eb2[e*32 + l32]

    const int rs = start_r[node], re = start_r[node + 1];
    const int cs = start_c[node], ce = start_c[node + 1];

    // ---- out-edge (row) gather of bf16 ea + a2 ride-along
    float4 ar0 = make_float4(0.f, 0.f, 0.f, 0.f), ar1 = ar0;
    float sa2 = 0.f;
    int j = rs;
    for (; j + 4 <= re; j += 4) {
        int2 p0 = row_pairs[j + half];
        int2 p1 = row_pairs[j + 2 + half];
        uint2 q0 = eb2[(size_t)p0.x * 32 + l32];
        uint2 q1 = eb2[(size_t)p1.x * 32 + l32];
        sa2 += __int_as_float(p0.y) + __int_as_float(p1.y);
        ar0.x += __uint_as_float(q0.x << 16); ar0.y += __uint_as_float(q0.x & 0xffff0000u);
        ar0.z += __uint_as_float(q0.y << 16); ar0.w += __uint_as_float(q0.y & 0xffff0000u);
        ar1.x += __uint_as_float(q1.x << 16); ar1.y += __uint_as_float(q1.x & 0xffff0000u);
        ar1.z += __uint_as_float(q1.y << 16); ar1.w += __uint_as_float(q1.y & 0xffff0000u);
    }
    for (; j + 2 <= re; j += 2) {
        int2 p0 = row_pairs[j + half];
        uint2 q0 = eb2[(size_t)p0.x * 32 + l32];
        sa2 += __int_as_float(p0.y);
        ar0.x += __uint_as_float(q0.x << 16); ar0.y += __uint_as_float(q0.x & 0xffff0000u);
        ar0.z += __uint_as_float(q0.y << 16); ar0.w += __uint_as_float(q0.y & 0xffff0000u);
    }
    if (j + half < re) {
        int2 p0 = row_pairs[j + half];
        uint2 q0 = eb2[(size_t)p0.x * 32 + l32];
        sa2 += __int_as_float(p0.y);
        ar0.x += __uint_as_float(q0.x << 16); ar0.y += __uint_as_float(q0.x & 0xffff0000u);
        ar0.z += __uint_as_float(q0.y << 16); ar0.w += __uint_as_float(q0.y & 0xffff0000u);
    }
    float4 ar;
    ar.x = ar0.x + ar1.x; ar.y = ar0.y + ar1.y; ar.z = ar0.z + ar1.z; ar.w = ar0.w + ar1.w;
    ar.x += __shfl_xor(ar.x, 32, 64); ar.y += __shfl_xor(ar.y, 32, 64);
    ar.z += __shfl_xor(ar.z, 32, 64); ar.w += __shfl_xor(ar.w, 32, 64);
    // ar duplicated across halves: lane holds comps 4*l32 .. 4*l32+3
    float s = wsum(sa2) * (1.f / 32.f);   // each edge's a2 counted by 32 lanes of its half

    // ---- in-edge (col) gather
    float4 ac0 = make_float4(0.f, 0.f, 0.f, 0.f), ac1 = ac0;
    j = cs;
    for (; j + 4 <= ce; j += 4) {
        int e0 = col_edges[j + half];
        int e1 = col_edges[j + 2 + half];
        uint2 q0 = eb2[(size_t)e0 * 32 + l32];
        uint2 q1 = eb2[(size_t)e1 * 32 + l32];
        ac0.x += __uint_as_float(q0.x << 16); ac0.y += __uint_as_float(q0.x & 0xffff0000u);
        ac0.z += __uint_as_float(q0.y << 16); ac0.w += __uint_as_float(q0.y & 0xffff0000u);
        ac1.x += __uint_as_float(q1.x << 16); ac1.y += __uint_as_float(q1.x & 0xffff0000u);
        ac1.z += __uint_as_float(q1.y << 16); ac1.w += __uint_as_float(q1.y & 0xffff0000u);
    }
    for (; j + 2 <= ce; j += 2) {
        int e0 = col_edges[j + half];
        uint2 q0 = eb2[(size_t)e0 * 32 + l32];
        ac0.x += __uint_as_float(q0.x << 16); ac0.y += __uint_as_float(q0.x & 0xffff0000u);
        ac0.z += __uint_as_float(q0.y << 16); ac0.w += __uint_as_float(q0.y & 0xffff0000u);
    }
    if (j + half < ce) {
        int e0 = col_edges[j + half];
        uint2 q0 = eb2[(size_t)e0 * 32 + l32];
        ac0.x += __uint_as_float(q0.x << 16); ac0.y += __uint_as_float(q0.x & 0xffff0000u);
        ac0.z += __uint_as_float(q0.y << 16); ac0.w += __uint_as_float(q0.y & 0xffff0000u);
    }
    float4 ac;
    ac.x = ac0.x + ac1.x; ac.y = ac0.y + ac1.y; ac.z = ac0.z + ac1.z; ac.w = ac0.w + ac1.w;
    ac.x += __shfl_xor(ac.x, 32, 64); ac.y += __shfl_xor(ac.y, 32, 64);
    ac.z += __shfl_xor(ac.z, 32, 64); ac.w += __shfl_xor(ac.w, 32, 64);

    // ---- d3 total = dot(w3, sum_out ea)   (duplicated halves -> x0.5)
    float4 w34 = ld4(attw + 256 + 4 * l32);
    float d3 = 0.5f * wsum(ar.x * w34.x + ar.y * w34.y + ar.z * w34.z + ar.w * w34.w);

    float degr = (float)(re - rs), degc = (float)(ce - cs);
    float satt = degr * (a1[node] + attb[0]) + s + d3;
    float mr = 1.f / fmaxf(degr, 1.f);
    float mc = 1.f / fmaxf(degc, 1.f);

    float4 xv = ld4(xt + (size_t)node * D + 4 * l32);
    float4 s4;
    s4.x = fmaf(xv.x, satt, xv.x) + ar.x * mr + ac.x * mc;
    s4.y = fmaf(xv.y, satt, xv.y) + ar.y * mr + ac.y * mc;
    s4.z = fmaf(xv.z, satt, xv.z) + ar.z * mr + ac.z * mc;
    s4.w = fmaf(xv.w, satt, xv.w) + ar.w * mr + ac.w * mc;

    // proj(expmap0(support))   (duplicated halves -> x0.5 on reductions)
    float n1 = fmaxf(sqrtf(0.5f * wsum(s4.x * s4.x + s4.y * s4.y + s4.z * s4.z + s4.w * s4.w)), 1e-15f);
    float th1 = tanhf(n1);
    float nrm1 = fminf(th1, 0.996f);
    float sc1 = nrm1 / n1;
    float lam = atanhf(fminf(nrm1, 1.f - 1e-7f)) / nrm1 * sc1;
    float4 t4;
    t4.x = fmaxf(lam * s4.x, 0.f); t4.y = fmaxf(lam * s4.y, 0.f);
    t4.z = fmaxf(lam * s4.z, 0.f); t4.w = fmaxf(lam * s4.w, 0.f);
    float n2 = fmaxf(sqrtf(0.5f * wsum(t4.x * t4.x + t4.y * t4.y + t4.z * t4.z + t4.w * t4.w)), 1e-15f);
    float th2 = tanhf(n2);
    float sc2 = fminf(th2, 0.996f) / n2;

    if (half == 0) {
        float4 o; o.x = sc2 * t4.x; o.y = sc2 * t4.y; o.z = sc2 * t4.z; o.w = sc2 * t4.w;
        *(float4*)(out + (size_t)node * D + 4 * l32) = o;
    }
}

// ----------------------------------------------------------------
extern "C" void kernel_launch(void* const* d_in, const int* in_sizes, int n_in,
                              void* d_out, int out_size, void* d_ws, size_t ws_size,
                              hipStream_t stream) {
    const float* x    = (const float*)d_in[0];
    const int*   adj  = (const int*)d_in[1];
    const float* ea   = (const float*)d_in[2];
    const float* W    = (const float*)d_in[3];
    const float* bias = (const float*)d_in[4];
    const float* attw = (const float*)d_in[5];
    const float* attb = (const float*)d_in[6];
    float* out = (float*)d_out;

    const int N = in_sizes[0] / D;   // 50000
    const int E = in_sizes[2] / D;   // 800000

    float* ws = (float*)d_ws;
    float* xt   = ws;  ws += (size_t)N * D;
    float* a1   = ws;  ws += N;
    float* a2   = ws;  ws += N;
    float* hb   = ws;  ws += D;
    float* hbsc = ws;  ws += 4;
    // float count so far is even -> 8B aligned here
    unsigned int* eb = (unsigned int*)ws;  ws += (size_t)E * (D / 2);   // E*64 uints
    int2* row_pairs  = (int2*)ws;          ws += (size_t)E * 2;
    int* iws = (int*)ws;
    int* col_edges = iws; iws += E;
    int* flag    = iws;  iws += 4;
    int* cnt_r   = iws;  iws += N;   // cnt_r|cnt_c contiguous for zeroing
    int* cnt_c   = iws;  iws += N;
    int* cur_r   = iws;  iws += N;
    int* cur_c   = iws;  iws += N;
    int* start_r = iws;  iws += N + 1;
    int* start_c = iws;  iws += N + 1;

    const int ZB = (2 * N + 255) / 256;
    initk<<<ZB + 2, 256, 0, stream>>>(adj, bias, attw, cnt_r, flag, hb, hbsc, 2 * N, ZB);

    const int P1B = (N + 31) / 32;   // phase1 blocks (4 waves x 8 nodes)
    const int CB  = 512;             // count blocks
    const int VB  = 2048;            // convert blocks
    fusedk<<<P1B + CB + VB, 256, 0, stream>>>(x, W, attw, hb, hbsc, adj, ea, flag,
                                              xt, a1, a2, cnt_r, cnt_c, eb, N, E,
                                              P1B, CB, VB);
    scank<<<2, 1024, 0, stream>>>(cnt_r, cnt_c, start_r, start_c, cur_r, cur_c, N);
    fillk<<<(E + 255) / 256, 256, 0, stream>>>(adj, a2, cur_r, cur_c, row_pairs, col_edges, flag, E);
    gatherk<<<(N * 64 + 255) / 256, 256, 0, stream>>>(eb, attw, attb, xt, a1,
                                                      start_r, start_c, row_pairs, col_edges,
                                                      out, N);
}

// Round 5
// 472.702 us; speedup vs baseline: 3.7432x; 1.3428x over previous
//
#include <hip/hip_runtime.h>
#include <math.h>

#define D 128

__device__ __forceinline__ float wsum(float v) {
    v += __shfl_xor(v, 1, 64);
    v += __shfl_xor(v, 2, 64);
    v += __shfl_xor(v, 4, 64);
    v += __shfl_xor(v, 8, 64);
    v += __shfl_xor(v, 16, 64);
    v += __shfl_xor(v, 32, 64);
    return v;
}

// reduce across the 32-lane group (lanes differing in bits 0..4)
__device__ __forceinline__ float hsum32(float v) {
    v += __shfl_xor(v, 1, 64);
    v += __shfl_xor(v, 2, 64);
    v += __shfl_xor(v, 4, 64);
    v += __shfl_xor(v, 8, 64);
    v += __shfl_xor(v, 16, 64);
    return v;
}

__device__ __forceinline__ float4 ld4(const float* p) { return *(const float4*)p; }
__device__ __forceinline__ float dot4(float4 a, float4 b) {
    return fmaf(a.x, b.x, fmaf(a.y, b.y, fmaf(a.z, b.z, a.w * b.w)));
}

__device__ __forceinline__ unsigned int bf16rne(float f) {
    unsigned int u = __float_as_uint(f);
    return (u + 0x7fffu + ((u >> 16) & 1u)) >> 16;
}

// ---------------------------------------------------------------- D1: zero | detect | bias | transpose-W
__global__ __launch_bounds__(256) void initk(const int* __restrict__ adj,
                                             const float* __restrict__ bias,
                                             const float* __restrict__ attw,
                                             const float* __restrict__ W,
                                             int* __restrict__ cnt,   // 2N ints
                                             int* __restrict__ flag,
                                             float* __restrict__ hb,
                                             float* __restrict__ hbsc,
                                             float* __restrict__ Wt,
                                             int n2, int ZB) {
    const int b = blockIdx.x;
    const int t = threadIdx.x;
    if (b < ZB) {
        int i = b * 256 + t;
        if (i < n2) cnt[i] = 0;
    } else if (b == ZB) {
        if (t < 64) {
            int v = adj[2 * t + 1];
            unsigned long long m = __ballot(v != 0);
            if (t == 0) *flag = (m == 0ULL) ? 1 : 0;
        }
    } else if (b == ZB + 1) {
        if (t < 64) {
            float b0 = bias[t], b1 = bias[t + 64];
            float n2f = wsum(b0 * b0 + b1 * b1);
            float n  = fmaxf(sqrtf(n2f), 1e-15f);
            float th = tanhf(n);
            float sc = th / n;
            float nn = th;
            if (nn > 0.996f) { sc *= 0.996f / nn; nn = 0.996f; }
            float h0 = sc * b0, h1 = sc * b1;
            hb[t] = h0; hb[t + 64] = h1;
            float s1 = wsum(attw[t] * h0 + attw[t + 64] * h1);
            float s2 = wsum(attw[128 + t] * h0 + attw[192 + t] * h1);
            if (t == 0) { hbsc[0] = nn * nn; hbsc[1] = s1; hbsc[2] = s2; }
        }
    } else {
        // transpose role: 4 blocks, each 32 k-rows of Wt
        int tb = b - (ZB + 2);              // 0..3
        int c = t & 127;
        int k0 = tb * 32 + (t >> 7) * 16;   // 16 k per thread
        float v[16];
#pragma unroll
        for (int j = 0; j < 4; ++j) {
            float4 r = ld4(W + (size_t)c * D + k0 + 4 * j);
            v[4 * j] = r.x; v[4 * j + 1] = r.y; v[4 * j + 2] = r.z; v[4 * j + 3] = r.w;
        }
#pragma unroll
        for (int j = 0; j < 16; ++j)
            Wt[(size_t)(k0 + j) * D + c] = v[j];   // coalesced across c
    }
}

// ---------------------------------------------------------------- D2: fused phase1-GEMM | count (striped 3:1)
__global__ __launch_bounds__(256) void fused1(const float* __restrict__ x,
                                              const float* __restrict__ Wt,
                                              const float* __restrict__ attw,
                                              const float* __restrict__ hb,
                                              const float* __restrict__ hbsc,
                                              const int* __restrict__ adj,
                                              const int* __restrict__ flag,
                                              float* __restrict__ xt,
                                              float* __restrict__ a1o,
                                              float* __restrict__ a2o,
                                              int* __restrict__ cnt_r,
                                              int* __restrict__ cnt_c,
                                              int N, int E, int CB) {
    const int b = blockIdx.x;
    const int t = threadIdx.x;
    __shared__ float Xs[32][128];

    if ((b & 3) == 3) {
        // ------- count role
        const int is64 = *flag;
        int cb = b >> 2;
        const int stride = CB * 256;
        for (int e = cb * 256 + t; e < E; e += stride) {
            int r, c;
            if (is64) { r = adj[(size_t)2 * e]; c = adj[2 * ((size_t)E + e)]; }
            else      { r = adj[e];             c = adj[(size_t)E + e]; }
            atomicAdd(&cnt_r[r], 1);
            atomicAdd(&cnt_c[c], 1);
        }
        return;
    }

    // ------- phase1 role: tile of 32 nodes
    const int pb = 3 * (b >> 2) + (b & 3);
    const int node0 = pb * 32;
    if (node0 >= N) return;

    // stage x tile (zero-pad tail rows)
    {
        int r = t >> 3;
        int cb4 = (t & 7) * 16;
        int gi = node0 + r;
        if (gi < N) {
            const float* src = x + (size_t)gi * D + cb4;
#pragma unroll
            for (int j = 0; j < 4; ++j)
                *(float4*)&Xs[r][cb4 + 4 * j] = ld4(src + 4 * j);
        } else {
            float4 z = make_float4(0.f, 0.f, 0.f, 0.f);
#pragma unroll
            for (int j = 0; j < 4; ++j)
                *(float4*)&Xs[r][cb4 + 4 * j] = z;
        }
    }
    __syncthreads();

    const int g  = t >> 5;          // node subgroup (4 nodes)
    const int cq = (t & 31) << 2;   // comp quad base

    float acc[4][4];
#pragma unroll
    for (int n = 0; n < 4; ++n)
#pragma unroll
        for (int c = 0; c < 4; ++c) acc[n][c] = 0.f;

    for (int k = 0; k < D; k += 4) {
        float4 w0 = ld4(Wt + (size_t)(k + 0) * D + cq);
        float4 w1 = ld4(Wt + (size_t)(k + 1) * D + cq);
        float4 w2 = ld4(Wt + (size_t)(k + 2) * D + cq);
        float4 w3 = ld4(Wt + (size_t)(k + 3) * D + cq);
#pragma unroll
        for (int n = 0; n < 4; ++n) {
            float4 xk = *(const float4*)&Xs[g * 4 + n][k];
            acc[n][0] = fmaf(xk.x, w0.x, fmaf(xk.y, w1.x, fmaf(xk.z, w2.x, fmaf(xk.w, w3.x, acc[n][0]))));
            acc[n][1] = fmaf(xk.x, w0.y, fmaf(xk.y, w1.y, fmaf(xk.z, w2.y, fmaf(xk.w, w3.y, acc[n][1]))));
            acc[n][2] = fmaf(xk.x, w0.z, fmaf(xk.y, w1.z, fmaf(xk.z, w2.z, fmaf(xk.w, w3.z, acc[n][2]))));
            acc[n][3] = fmaf(xk.x, w0.w, fmaf(xk.y, w1.w, fmaf(xk.z, w2.w, fmaf(xk.w, w3.w, acc[n][3]))));
        }
    }

    float4 hb4 = ld4(hb + cq);
    float4 w14 = ld4(attw + cq);
    float4 w24 = ld4(attw + 128 + cq);
    const float hb2 = hbsc[0], s1 = hbsc[1], s2 = hbsc[2];

#pragma unroll
    for (int n = 0; n < 4; ++n) {
        const int i = node0 + g * 4 + n;
        float4 mx = make_float4(acc[n][0], acc[n][1], acc[n][2], acc[n][3]);
        float4 xv = *(const float4*)&Xs[g * 4 + n][cq];

        float xn2  = hsum32(dot4(xv, xv));
        float mxn2 = hsum32(dot4(mx, mx));
        float dmb  = hsum32(dot4(mx, hb4));
        float r1   = hsum32(dot4(mx, w14));
        float r2   = hsum32(dot4(mx, w24));

        float xn  = fmaxf(sqrtf(xn2), 1e-15f);
        float mxn = fmaxf(sqrtf(mxn2), 1e-15f);
        float art = atanhf(fminf(xn, 1.f - 1e-7f));
        float th  = tanhf(mxn / xn * art);
        float hnorm = fminf(th, 0.996f);
        float alpha = hnorm / mxn;
        float x2 = hnorm * hnorm, xy = alpha * dmb;
        float den = fmaxf(1.f + 2.f * xy + x2 * hb2, 1e-15f);
        float cA = (1.f + 2.f * xy + hb2) / den * alpha;
        float cB = (1.f - x2) / den;
        float h2n2 = cA * cA * mxn2 + 2.f * cA * cB * dmb + cB * cB * hb2;
        float h2n = fmaxf(sqrtf(h2n2), 1e-15f);
        if (h2n > 0.996f) { float sl = 0.996f / h2n; cA *= sl; cB *= sl; h2n = 0.996f; }
        float gg = atanhf(fminf(h2n, 1.f - 1e-7f)) / h2n;
        cA *= gg; cB *= gg;

        if (i < N) {
            float4 o;
            o.x = cA * mx.x + cB * hb4.x; o.y = cA * mx.y + cB * hb4.y;
            o.z = cA * mx.z + cB * hb4.z; o.w = cA * mx.w + cB * hb4.w;
            *(float4*)(xt + (size_t)i * D + cq) = o;
            if ((t & 31) == 0) {
                a1o[i] = cA * r1 + cB * s1;
                a2o[i] = cA * r2 + cB * s2;
            }
        }
    }
}

// ---------------------------------------------------------------- D3: exclusive scan
__global__ __launch_bounds__(1024) void scank(const int* __restrict__ cnt_r,
                                              const int* __restrict__ cnt_c,
                                              int* __restrict__ start_r,
                                              int* __restrict__ start_c,
                                              int* __restrict__ cur_r,
                                              int* __restrict__ cur_c,
                                              int N) {
    const int* cnt  = blockIdx.x == 0 ? cnt_r : cnt_c;
    int* start      = blockIdx.x == 0 ? start_r : start_c;
    int* cur        = blockIdx.x == 0 ? cur_r : cur_c;
    const int t = threadIdx.x;
    const int NT = 1024;
    const int CH = (N + NT - 1) / NT;
    const int lo = t * CH;
    int hi = lo + CH; if (hi > N) hi = N;

    int local = 0;
    for (int i = lo; i < hi; ++i) local += cnt[i];

    __shared__ int sm[1024];
    sm[t] = local;
    __syncthreads();
    for (int off = 1; off < 1024; off <<= 1) {
        int v = (t >= off) ? sm[t - off] : 0;
        __syncthreads();
        sm[t] += v;
        __syncthreads();
    }
    int run = sm[t] - local;
    for (int i = lo; i < hi; ++i) {
        start[i] = run;
        cur[i] = run;
        run += cnt[i];
    }
    if (t == NT - 1) start[N] = sm[NT - 1];
}

// ---------------------------------------------------------------- D4: fused fill | bf16-convert (striped 1:1)
__global__ __launch_bounds__(256) void fused2(const int* __restrict__ adj,
                                              const float* __restrict__ a2,
                                              const float* __restrict__ ea,
                                              int* __restrict__ cur_r,
                                              int* __restrict__ cur_c,
                                              int2* __restrict__ row_pairs,
                                              int* __restrict__ col_edges,
                                              unsigned int* __restrict__ eb,
                                              const int* __restrict__ flag,
                                              int E, int FB) {
    const int b = blockIdx.x;
    const int t = threadIdx.x;
    if ((b & 1) == 0) {
        // ------- fill role
        int e = (b >> 1) * 256 + t;
        if (e >= E) return;
        int r, c;
        if (*flag) { r = adj[(size_t)2 * e]; c = adj[2 * ((size_t)E + e)]; }
        else       { r = adj[e];             c = adj[(size_t)E + e]; }
        int p = atomicAdd(&cur_r[r], 1);
        row_pairs[p] = make_int2(e, __float_as_int(a2[c]));
        int q = atomicAdd(&cur_c[c], 1);
        col_edges[q] = e;
    } else {
        // ------- convert role
        const long long F4 = (long long)E * (D / 4);
        const long long stride = (long long)FB * 256;
        const float4* ea4 = (const float4*)ea;
        uint2* eb2 = (uint2*)eb;
        for (long long f = (long long)(b >> 1) * 256 + t; f < F4; f += stride) {
            float4 v = ea4[f];
            uint2 o;
            o.x = bf16rne(v.x) | (bf16rne(v.y) << 16);
            o.y = bf16rne(v.z) | (bf16rne(v.w) << 16);
            eb2[f] = o;
        }
    }
}

// ---------------------------------------------------------------- D5: fused gather (bf16) + phase 3
__global__ __launch_bounds__(256) void gatherk(const unsigned int* __restrict__ eb,
                                               const float* __restrict__ attw,
                                               const float* __restrict__ attb,
                                               const float* __restrict__ xt,
                                               const float* __restrict__ a1,
                                               const int* __restrict__ start_r,
                                               const int* __restrict__ start_c,
                                               const int2* __restrict__ row_pairs,
                                               const int* __restrict__ col_edges,
                                               float* __restrict__ out,
                                               int N) {
    const int lane = threadIdx.x & 63;
    const int half = lane >> 5;
    const int l32  = lane & 31;
    const int node = (blockIdx.x * blockDim.x + threadIdx.x) >> 6;
    if (node >= N) return;
    const uint2* eb2 = (const uint2*)eb;

    const int rs = start_r[node], re = start_r[node + 1];
    const int cs = start_c[node], ce = start_c[node + 1];

    float4 ar0 = make_float4(0.f, 0.f, 0.f, 0.f), ar1 = ar0;
    float sa2 = 0.f;
    int j = rs;
    for (; j + 4 <= re; j += 4) {
        int2 p0 = row_pairs[j + half];
        int2 p1 = row_pairs[j + 2 + half];
        uint2 q0 = eb2[(size_t)p0.x * 32 + l32];
        uint2 q1 = eb2[(size_t)p1.x * 32 + l32];
        sa2 += __int_as_float(p0.y) + __int_as_float(p1.y);
        ar0.x += __uint_as_float(q0.x << 16); ar0.y += __uint_as_float(q0.x & 0xffff0000u);
        ar0.z += __uint_as_float(q0.y << 16); ar0.w += __uint_as_float(q0.y & 0xffff0000u);
        ar1.x += __uint_as_float(q1.x << 16); ar1.y += __uint_as_float(q1.x & 0xffff0000u);
        ar1.z += __uint_as_float(q1.y << 16); ar1.w += __uint_as_float(q1.y & 0xffff0000u);
    }
    for (; j + 2 <= re; j += 2) {
        int2 p0 = row_pairs[j + half];
        uint2 q0 = eb2[(size_t)p0.x * 32 + l32];
        sa2 += __int_as_float(p0.y);
        ar0.x += __uint_as_float(q0.x << 16); ar0.y += __uint_as_float(q0.x & 0xffff0000u);
        ar0.z += __uint_as_float(q0.y << 16); ar0.w += __uint_as_float(q0.y & 0xffff0000u);
    }
    if (j + half < re) {
        int2 p0 = row_pairs[j + half];
        uint2 q0 = eb2[(size_t)p0.x * 32 + l32];
        sa2 += __int_as_float(p0.y);
        ar0.x += __uint_as_float(q0.x << 16); ar0.y += __uint_as_float(q0.x & 0xffff0000u);
        ar0.z += __uint_as_float(q0.y << 16); ar0.w += __uint_as_float(q0.y & 0xffff0000u);
    }
    float4 ar;
    ar.x = ar0.x + ar1.x; ar.y = ar0.y + ar1.y; ar.z = ar0.z + ar1.z; ar.w = ar0.w + ar1.w;
    ar.x += __shfl_xor(ar.x, 32, 64); ar.y += __shfl_xor(ar.y, 32, 64);
    ar.z += __shfl_xor(ar.z, 32, 64); ar.w += __shfl_xor(ar.w, 32, 64);
    float s = wsum(sa2) * (1.f / 32.f);

    float4 ac0 = make_float4(0.f, 0.f, 0.f, 0.f), ac1 = ac0;
    j = cs;
    for (; j + 4 <= ce; j += 4) {
        int e0 = col_edges[j + half];
        int e1 = col_edges[j + 2 + half];
        uint2 q0 = eb2[(size_t)e0 * 32 + l32];
        uint2 q1 = eb2[(size_t)e1 * 32 + l32];
        ac0.x += __uint_as_float(q0.x << 16); ac0.y += __uint_as_float(q0.x & 0xffff0000u);
        ac0.z += __uint_as_float(q0.y << 16); ac0.w += __uint_as_float(q0.y & 0xffff0000u);
        ac1.x += __uint_as_float(q1.x << 16); ac1.y += __uint_as_float(q1.x & 0xffff0000u);
        ac1.z += __uint_as_float(q1.y << 16); ac1.w += __uint_as_float(q1.y & 0xffff0000u);
    }
    for (; j + 2 <= ce; j += 2) {
        int e0 = col_edges[j + half];
        uint2 q0 = eb2[(size_t)e0 * 32 + l32];
        ac0.x += __uint_as_float(q0.x << 16); ac0.y += __uint_as_float(q0.x & 0xffff0000u);
        ac0.z += __uint_as_float(q0.y << 16); ac0.w += __uint_as_float(q0.y & 0xffff0000u);
    }
    if (j + half < ce) {
        int e0 = col_edges[j + half];
        uint2 q0 = eb2[(size_t)e0 * 32 + l32];
        ac0.x += __uint_as_float(q0.x << 16); ac0.y += __uint_as_float(q0.x & 0xffff0000u);
        ac0.z += __uint_as_float(q0.y << 16); ac0.w += __uint_as_float(q0.y & 0xffff0000u);
    }
    float4 ac;
    ac.x = ac0.x + ac1.x; ac.y = ac0.y + ac1.y; ac.z = ac0.z + ac1.z; ac.w = ac0.w + ac1.w;
    ac.x += __shfl_xor(ac.x, 32, 64); ac.y += __shfl_xor(ac.y, 32, 64);
    ac.z += __shfl_xor(ac.z, 32, 64); ac.w += __shfl_xor(ac.w, 32, 64);

    float4 w34 = ld4(attw + 256 + 4 * l32);
    float d3 = 0.5f * wsum(ar.x * w34.x + ar.y * w34.y + ar.z * w34.z + ar.w * w34.w);

    float degr = (float)(re - rs), degc = (float)(ce - cs);
    float satt = degr * (a1[node] + attb[0]) + s + d3;
    float mr = 1.f / fmaxf(degr, 1.f);
    float mc = 1.f / fmaxf(degc, 1.f);

    float4 xv = ld4(xt + (size_t)node * D + 4 * l32);
    float4 s4;
    s4.x = fmaf(xv.x, satt, xv.x) + ar.x * mr + ac.x * mc;
    s4.y = fmaf(xv.y, satt, xv.y) + ar.y * mr + ac.y * mc;
    s4.z = fmaf(xv.z, satt, xv.z) + ar.z * mr + ac.z * mc;
    s4.w = fmaf(xv.w, satt, xv.w) + ar.w * mr + ac.w * mc;

    float n1 = fmaxf(sqrtf(0.5f * wsum(s4.x * s4.x + s4.y * s4.y + s4.z * s4.z + s4.w * s4.w)), 1e-15f);
    float th1 = tanhf(n1);
    float nrm1 = fminf(th1, 0.996f);
    float sc1 = nrm1 / n1;
    float lam = atanhf(fminf(nrm1, 1.f - 1e-7f)) / nrm1 * sc1;
    float4 t4;
    t4.x = fmaxf(lam * s4.x, 0.f); t4.y = fmaxf(lam * s4.y, 0.f);
    t4.z = fmaxf(lam * s4.z, 0.f); t4.w = fmaxf(lam * s4.w, 0.f);
    float n2 = fmaxf(sqrtf(0.5f * wsum(t4.x * t4.x + t4.y * t4.y + t4.z * t4.z + t4.w * t4.w)), 1e-15f);
    float th2 = tanhf(n2);
    float sc2 = fminf(th2, 0.996f) / n2;

    if (half == 0) {
        float4 o; o.x = sc2 * t4.x; o.y = sc2 * t4.y; o.z = sc2 * t4.z; o.w = sc2 * t4.w;
        *(float4*)(out + (size_t)node * D + 4 * l32) = o;
    }
}

// ----------------------------------------------------------------
extern "C" void kernel_launch(void* const* d_in, const int* in_sizes, int n_in,
                              void* d_out, int out_size, void* d_ws, size_t ws_size,
                              hipStream_t stream) {
    const float* x    = (const float*)d_in[0];
    const int*   adj  = (const int*)d_in[1];
    const float* ea   = (const float*)d_in[2];
    const float* W    = (const float*)d_in[3];
    const float* bias = (const float*)d_in[4];
    const float* attw = (const float*)d_in[5];
    const float* attb = (const float*)d_in[6];
    float* out = (float*)d_out;

    const int N = in_sizes[0] / D;   // 50000
    const int E = in_sizes[2] / D;   // 800000

    float* ws = (float*)d_ws;
    float* xt   = ws;  ws += (size_t)N * D;
    float* a1   = ws;  ws += N;
    float* a2   = ws;  ws += N;
    float* hb   = ws;  ws += D;
    float* hbsc = ws;  ws += 4;
    float* Wt   = ws;  ws += D * D;
    unsigned int* eb = (unsigned int*)ws;  ws += (size_t)E * (D / 2);
    int2* row_pairs  = (int2*)ws;          ws += (size_t)E * 2;
    int* iws = (int*)ws;
    int* col_edges = iws; iws += E;
    int* flag    = iws;  iws += 4;
    int* cnt_r   = iws;  iws += N;   // cnt_r|cnt_c contiguous
    int* cnt_c   = iws;  iws += N;
    int* cur_r   = iws;  iws += N;
    int* cur_c   = iws;  iws += N;
    int* start_r = iws;  iws += N + 1;
    int* start_c = iws;  iws += N + 1;

    const int ZB = (2 * N + 255) / 256;
    initk<<<ZB + 6, 256, 0, stream>>>(adj, bias, attw, W, cnt_r, flag, hb, hbsc, Wt, 2 * N, ZB);

    // fused1: phase1 (3 of every 4 blocks) | count (1 of 4)
    const int P1B  = (N + 31) / 32;
    const int CB   = (P1B + 2) / 3;     // count blocks
    const int G1   = 4 * CB;            // covers pb in [0, 3*CB) >= P1B
    fused1<<<G1, 256, 0, stream>>>(x, Wt, attw, hb, hbsc, adj, flag,
                                   xt, a1, a2, cnt_r, cnt_c, N, E, CB);
    scank<<<2, 1024, 0, stream>>>(cnt_r, cnt_c, start_r, start_c, cur_r, cur_c, N);

    const int FB = (E + 255) / 256;
    fused2<<<2 * FB, 256, 0, stream>>>(adj, a2, ea, cur_r, cur_c, row_pairs, col_edges, eb, flag, E, FB);

    gatherk<<<(N * 64 + 255) / 256, 256, 0, stream>>>(eb, attw, attb, xt, a1,
                                                      start_r, start_c, row_pairs, col_edges,
                                                      out, N);
}